// Round 15
// baseline (139.404 us; speedup 1.0000x reference)
//
#include <hip/hip_runtime.h>
#include <cstddef>

#define H_IN 1024
#define W_IN 1024
#define BN_EPS 1e-5f

typedef float f32x4 __attribute__((ext_vector_type(4)));
typedef _Float16 f16x8 __attribute__((ext_vector_type(8)));

// order-preserving float<->u32 bijection: enc monotonic, enc(x)>0 for all reals,
// so 0x00000000 is the identity for unsigned atomicMax.
__device__ __forceinline__ unsigned encF(float f) {
    unsigned u = __float_as_uint(f);
    return (u & 0x80000000u) ? ~u : (u | 0x80000000u);
}
__device__ __forceinline__ float decF(unsigned e, float untouched) {
    if (e == 0u) return untouched;
    unsigned bits = (e & 0x80000000u) ? (e ^ 0x80000000u) : ~e;
    return __uint_as_float(bits);
}

// ---------------- stage -1: zero bev + prep conv3 weights (one launch) ----------------
// blocks 0..2047: uint4-zero the 33.5MB bev. blocks 2048..2056: wprep tap blockIdx-2048.
__global__ void k_prep(uint4* __restrict__ bevq,
                       const float* __restrict__ w3, const float* __restrict__ b3,
                       const float* __restrict__ g3, const float* __restrict__ be3,
                       const float* __restrict__ m3, const float* __restrict__ v3,
                       _Float16* __restrict__ wh, float* __restrict__ tv) {
    int bid = blockIdx.x;
    int t = threadIdx.x;
    if (bid < 2048) {
        int i = bid * 256 + t;
        uint4 z = {0u, 0u, 0u, 0u};
        #pragma unroll
        for (int j = 0; j < 4; j++)
            bevq[(size_t)j*524288 + i] = z;
        return;
    }
    __shared__ float sSh[64];
    if (t < 64) {
        float s = g3[t] / sqrtf(v3[t] + BN_EPS);
        sSh[t] = s;
        if (bid == 2048) tv[t] = (b3[t] - m3[t]) * s + be3[t];
    }
    __syncthreads();
    int khw = bid - 2048;
    for (int i = t; i < 2048; i += 256) {
        int oc = i >> 5;                       // i = oc*32 + ic
        wh[khw*2048 + i] = (_Float16)(w3[(size_t)i*9 + khw] * sSh[oc]);
    }
}

// ---------------- stage 0: rasterize into encoded interleaved BEV ----------------
// r10/r13/r14 measured: 1pt/thread == 4pt-loop == 8pt-phase-batch (all ~41 us) ->
// bound by device-scope scattered atomic RMW throughput (~23G/s), not latency or
// layout. Simplest form kept; this is a hardware wall for the atomic approach.
__global__ void k_rasterize(const float* __restrict__ pts, unsigned* __restrict__ bev, int n) {
    int i = blockIdx.x * blockDim.x + threadIdx.x;
    if (i >= n) return;
    float fb  = pts[(size_t)i*5+0];
    float px  = pts[(size_t)i*5+1];
    float py  = pts[(size_t)i*5+2];
    float pz  = pts[(size_t)i*5+3];
    float pit = pts[(size_t)i*5+4];
    const float XS = (float)(1024.0/69.12);
    const float YS = (float)(1024.0/79.36);
    int xp = (int)(px * XS);                  // trunc toward zero, same as astype(int32)
    int yp = (int)((py + 39.68f) * YS);
    if (xp < 0 || xp >= W_IN || yp < 0 || yp >= H_IN) return;
    int b = (int)fb;
    size_t off = (((size_t)b * H_IN + yp) * W_IN + xp) * 2;
    atomicMax(bev + off,     encF(pz));
    atomicMax(bev + off + 1, encF(pit));
}

// ---------------- stage 1: conv1(2->8,3x3,pad1)+BN+ReLU+maxpool2 -> f16 NHWC ----------------
// in:  bev u32 [4,1024,1024,2] encoded   out: x1h [4,512,512,8] f16 (NHWC: one 16B store)
__global__ __launch_bounds__(256, 4) void k_conv1(
                        const unsigned* __restrict__ bev, const float* __restrict__ w0,
                        const float* __restrict__ b0, const float* __restrict__ g0,
                        const float* __restrict__ be0, const float* __restrict__ m0,
                        const float* __restrict__ v0, _Float16* __restrict__ out) {
    __shared__ float wS[144];       // [8][2][3][3]
    __shared__ float sS[8], tS[8];
    int t = threadIdx.x;
    if (t < 144) wS[t] = w0[t];
    if (t < 8) {
        float s = g0[t] / sqrtf(v0[t] + BN_EPS);
        sS[t] = s;
        tS[t] = (b0[t] - m0[t]) * s + be0[t];
    }
    __syncthreads();
    int idx = blockIdx.x * 256 + t;                 // 4*512*512 total
    int x = idx & 511, y = (idx >> 9) & 511, b = idx >> 18;
    const unsigned* base = bev + (size_t)b * H_IN * W_IN * 2;
    float in[2][4][4];
    #pragma unroll
    for (int r = 0; r < 4; r++) {
        int iy = 2*y - 1 + r;
        #pragma unroll
        for (int cc = 0; cc < 4; cc++) {
            int ix = 2*x - 1 + cc;
            if (iy >= 0 && iy < H_IN && ix >= 0 && ix < W_IN) {
                const unsigned* p2 = base + ((size_t)iy*W_IN + ix)*2;
                in[0][r][cc] = decF(p2[0], -10.0f);
                in[1][r][cc] = decF(p2[1], 0.0f);
            } else {
                in[0][r][cc] = 0.0f;
                in[1][r][cc] = 0.0f;
            }
        }
    }
    f16x8 ov;
    #pragma unroll
    for (int oc = 0; oc < 8; oc++) {
        float mx = 0.0f;                            // post-ReLU values are >= 0
        #pragma unroll
        for (int py = 0; py < 2; py++)
            #pragma unroll
            for (int px = 0; px < 2; px++) {
                float acc = 0.0f;
                #pragma unroll
                for (int c = 0; c < 2; c++)
                    #pragma unroll
                    for (int kh = 0; kh < 3; kh++)
                        #pragma unroll
                        for (int kw = 0; kw < 3; kw++)
                            acc += in[c][py+kh][px+kw] * wS[((oc*2+c)*3+kh)*3+kw];
                acc = fmaxf(acc * sS[oc] + tS[oc], 0.0f);
                mx = fmaxf(mx, acc);
            }
        ov[oc] = (_Float16)mx;
    }
    *(f16x8*)(out + ((size_t)((b*512 + y)*512 + x)) * 8) = ov;
}

// ---------------- fused stage 2+3: conv2(grouped)+BN+ReLU+pool -> dw+pw+BN+ReLU -> f16 NHWC ----------------
// in: x1h [4,512,512,8] f16 NHWC   out: x3h [4,256,256,32] f16
// r15 fusion: x2 never touches HBM (saves 33.6 MB round-trip + 1 dispatch gap).
// Phase 1: stage x1h halo 22x70x8 -> channel-planar LDS [8][22][72] (conflict-free
//          phase-2 reads; 2B-pair staging writes are 2-way = free).
// Phase 2: conv2+pool -> x2S [16][10][36] f32 in LDS. Out-of-range x2 pixels are
//          FORCED to 0 (dwpw's zero-pad; conv2-of-zero-x1 is NOT 0 -- r8 lesson).
// Phase 3: dw+pw from x2S (identical to r5-validated dwpw phase).
__global__ __launch_bounds__(256, 3) void k_conv2dw(
        const _Float16* __restrict__ x1,
        const float* __restrict__ w1, const float* __restrict__ b1,
        const float* __restrict__ g1, const float* __restrict__ be1,
        const float* __restrict__ m1, const float* __restrict__ v1,
        const float* __restrict__ wdw, const float* __restrict__ bdw,
        const float* __restrict__ wpw, const float* __restrict__ bpw,
        const float* __restrict__ g2, const float* __restrict__ be2,
        const float* __restrict__ m2, const float* __restrict__ v2,
        _Float16* __restrict__ out) {
    __shared__ _Float16 x1S[8][22][72];     // 25344 B, channel-planar
    __shared__ float x2S[16][10][36];       // 23040 B
    __shared__ float w1S[144], s1S[16], t1S[16];
    __shared__ float wdwS[144], bdwS[16], wpwS[512], s2S[32], t2S[32];
    int t = threadIdx.x;
    if (t < 144) { w1S[t] = w1[t]; wdwS[t] = wdw[t]; }
    if (t < 16) {
        float s = g1[t] / sqrtf(v1[t] + BN_EPS);
        s1S[t] = s; t1S[t] = (b1[t] - m1[t]) * s + be1[t];
        bdwS[t] = bdw[t];
    }
    for (int i = t; i < 512; i += 256) wpwS[i] = wpw[i];
    if (t < 32) {
        float s = g2[t] / sqrtf(v2[t] + BN_EPS);
        s2S[t] = s; t2S[t] = (bpw[t] - m2[t]) * s + be2[t];
    }
    int bi = blockIdx.x;               // 1024 = 8 tx * 32 ty * 4 b
    int tx = bi & 7, ty = (bi >> 3) & 31, b = bi >> 8;
    int x0 = tx * 32, y0 = ty * 8;     // x3h tile origin (256 grid)

    // phase 1: stage x1h rows 2y0-3..2y0+18 (22), cols 2x0-3..2x0+66 (70)
    const _Float16* base1 = x1 + (size_t)b * 512 * 512 * 8;
    int ry0 = 2*y0 - 3, cx0 = 2*x0 - 3;
    for (int i = t; i < 22*70; i += 256) {
        int r = i / 70, c = i - r*70;
        int gy = ry0 + r, gx = cx0 + c;
        f16x8 v = {0,0,0,0,0,0,0,0};
        if (gy >= 0 && gy < 512 && gx >= 0 && gx < 512)
            v = *(const f16x8*)(base1 + ((size_t)gy*512 + gx)*8);
        #pragma unroll
        for (int j = 0; j < 8; j++)
            x1S[j][r][c] = v[j];
    }
    __syncthreads();

    // phase 2: conv2 grouped + BN + ReLU + pool -> x2S halo [16][10][34(+2 pad)]
    for (int i = t; i < 340; i += 256) {
        int r = i / 34, c = i - r*34;
        int gy = y0 - 1 + r, gx = x0 - 1 + c;
        bool valid = (gy >= 0 && gy < 256 && gx >= 0 && gx < 256);
        // pre-pool local origin: rows 2r..2r+3, cols 2c..2c+3 (verified: (2gy-1)-ry0 = 2r)
        #pragma unroll
        for (int g = 0; g < 8; g++) {
            float p[4][4];
            #pragma unroll
            for (int rr = 0; rr < 4; rr++)
                #pragma unroll
                for (int cc = 0; cc < 4; cc++)
                    p[rr][cc] = (float)x1S[g][2*r + rr][2*c + cc];
            #pragma unroll
            for (int sub = 0; sub < 2; sub++) {
                int oc = g*2 + sub;
                float mx = 0.0f;
                #pragma unroll
                for (int qy = 0; qy < 2; qy++)
                    #pragma unroll
                    for (int qx = 0; qx < 2; qx++) {
                        float acc = 0.0f;
                        #pragma unroll
                        for (int kh = 0; kh < 3; kh++)
                            #pragma unroll
                            for (int kw = 0; kw < 3; kw++)
                                acc += p[qy+kh][qx+kw] * w1S[(oc*3+kh)*3+kw];
                        acc = fmaxf(acc * s1S[oc] + t1S[oc], 0.0f);
                        mx = fmaxf(mx, acc);
                    }
                x2S[oc][r][c] = valid ? mx : 0.0f;
            }
        }
    }
    __syncthreads();

    // phase 3: depthwise + pointwise from x2S -> x3h f16 NHWC
    int px = t & 31, pyy = t >> 5;
    int x = x0 + px, y = y0 + pyy;
    float dv[16];
    #pragma unroll
    for (int ic = 0; ic < 16; ic++) {
        float d = bdwS[ic];
        #pragma unroll
        for (int r = 0; r < 3; r++)
            #pragma unroll
            for (int c = 0; c < 3; c++)
                d += x2S[ic][pyy + r][px + c] * wdwS[ic*9 + r*3 + c];
        dv[ic] = d;
    }
    _Float16* ob = out + ((size_t)((b*256 + y)*256 + x)) * 32;
    #pragma unroll
    for (int q = 0; q < 4; q++) {
        f16x8 ov;
        #pragma unroll
        for (int j = 0; j < 8; j++) {
            int oc = q*8 + j;
            float a = 0.0f;
            #pragma unroll
            for (int ic = 0; ic < 16; ic++)
                a += dv[ic] * wpwS[oc*16+ic];
            ov[j] = (_Float16)fmaxf(a*s2S[oc] + t2S[oc], 0.0f);
        }
        *(f16x8*)(ob + q*8) = ov;
    }
}

// ---------------- stage 4: conv3 via MFMA f16 implicit GEMM + BN + ReLU + maxpool2 ----------------
// in: x3h [4,256,256,32] f16 NHWC, wh [9][64][32] f16, tv[64] f32
// out: d_out [4,64,128,128] f32
// r8-validated: stage 10 rows ONCE per block (52.8 KB LDS), 1 barrier, 4 row-tiles.
__global__ __launch_bounds__(256, 2) void k_conv3m(const _Float16* __restrict__ xh,
                                                   const _Float16* __restrict__ wh,
                                                   const float* __restrict__ tv,
                                                   float* __restrict__ out) {
    __shared__ _Float16 As[10*66*40];       // rows x px x ic(pad 32->40), 52800 B
    int t = threadIdx.x;
    int lane = t & 63, w = t >> 6;
    int l15 = lane & 15, l4 = lane >> 4;
    int bi = blockIdx.x;
    int xt = bi & 3, yg = (bi >> 2) & 31, b = bi >> 7;
    int x0 = xt * 64;
    int y0 = yg * 8;                        // pre-pool row base (256-grid)

    f16x8 Bf[9][4];
    #pragma unroll
    for (int khw = 0; khw < 9; khw++)
        #pragma unroll
        for (int g = 0; g < 4; g++)
            Bf[khw][g] = *(const f16x8*)(wh + ((khw*64 + g*16 + l15)*32 + 8*l4));

    float tvv[4];
    #pragma unroll
    for (int g = 0; g < 4; g++) tvv[g] = tv[g*16 + l15];

    for (int s = t; s < 660; s += 256) {
        int row = s / 66, px = s - row*66;
        int gy = y0 - 1 + row, gx = x0 - 1 + px;
        float4* dst = (float4*)&As[(row*66 + px)*40];
        if (gy >= 0 && gy < 256 && gx >= 0 && gx < 256) {
            const float4* src = (const float4*)(xh + ((size_t)((b*256 + gy)*256 + gx)) * 32);
            #pragma unroll
            for (int j = 0; j < 4; j++) dst[j] = src[j];
        } else {
            float4 z = make_float4(0.f, 0.f, 0.f, 0.f);
            #pragma unroll
            for (int j = 0; j < 4; j++) dst[j] = z;
        }
    }
    __syncthreads();

    for (int ti = 0; ti < 4; ti++) {
        int ypool = yg*4 + ti;              // pooled row 0..127
        f32x4 acc[2][4];
        #pragma unroll
        for (int f = 0; f < 2; f++)
            #pragma unroll
            for (int g = 0; g < 4; g++)
                acc[f][g] = (f32x4){0.f, 0.f, 0.f, 0.f};

        #pragma unroll
        for (int kh = 0; kh < 3; kh++)
            #pragma unroll
            for (int kw = 0; kw < 3; kw++) {
                f16x8 Af[2];
                #pragma unroll
                for (int f = 0; f < 2; f++) {
                    int row = 2*ti + f + kh;                // staged row idx
                    int px = w*16 + l15 + kw;               // staged px idx
                    Af[f] = *(const f16x8*)&As[(row*66 + px)*40 + 8*l4];
                }
                #pragma unroll
                for (int f = 0; f < 2; f++)
                    #pragma unroll
                    for (int g = 0; g < 4; g++)
                        acc[f][g] = __builtin_amdgcn_mfma_f32_16x16x32_f16(
                            Af[f], Bf[kh*3+kw][g], acc[f][g], 0, 0, 0);
            }

        #pragma unroll
        for (int g = 0; g < 4; g++) {
            int oc = g*16 + l15;
            #pragma unroll
            for (int q = 0; q < 2; q++) {
                float v0 = fmaxf(fmaxf(acc[0][g][2*q]   + tvv[g], 0.f),
                                 fmaxf(acc[0][g][2*q+1] + tvv[g], 0.f));
                float v1 = fmaxf(fmaxf(acc[1][g][2*q]   + tvv[g], 0.f),
                                 fmaxf(acc[1][g][2*q+1] + tvv[g], 0.f));
                int px = x0/2 + w*8 + 2*l4 + q;
                out[(((size_t)b*64 + oc)*128 + ypool)*128 + px] = fmaxf(v0, v1);
            }
        }
    }
}

extern "C" void kernel_launch(void* const* d_in, const int* in_sizes, int n_in,
                              void* d_out, int out_size, void* d_ws, size_t ws_size,
                              hipStream_t stream) {
    const float* points = (const float*)d_in[0];
    int n = in_sizes[0] / 5;
    const float* w0  = (const float*)d_in[2];
    const float* b0  = (const float*)d_in[3];
    const float* g0  = (const float*)d_in[4];
    const float* be0 = (const float*)d_in[5];
    const float* m0  = (const float*)d_in[6];
    const float* v0  = (const float*)d_in[7];
    const float* w1  = (const float*)d_in[8];
    const float* b1  = (const float*)d_in[9];
    const float* g1  = (const float*)d_in[10];
    const float* be1 = (const float*)d_in[11];
    const float* m1  = (const float*)d_in[12];
    const float* v1  = (const float*)d_in[13];
    const float* wdw = (const float*)d_in[14];
    const float* bdw = (const float*)d_in[15];
    const float* wpw = (const float*)d_in[16];
    const float* bpw = (const float*)d_in[17];
    const float* g2  = (const float*)d_in[18];
    const float* be2 = (const float*)d_in[19];
    const float* m2  = (const float*)d_in[20];
    const float* v2  = (const float*)d_in[21];
    const float* w3  = (const float*)d_in[22];
    const float* b3  = (const float*)d_in[23];
    const float* g3  = (const float*)d_in[24];
    const float* be3 = (const float*)d_in[25];
    const float* m3  = (const float*)d_in[26];
    const float* v3  = (const float*)d_in[27];

    float* ws  = (float*)d_ws;
    // layout (float indices into ws):
    //   bev  u32 [4,1024,1024,2] : 0 .. 8,388,608          (dead after conv1)
    //   x1h  f16 [4,512,512,8]   : 8,388,608 .. 12,582,912 (dead after conv2dw)
    //   x3h  f16 [4,256,256,32]  : 0 .. 4,194,304          (reuses bev region; conv1
    //                                finished before conv2dw writes it. NOT x1h's
    //                                region: conv2dw reads x1h while writing x3h!)
    //   wh   f16 [9][64][32]     : 16,777,216 ..           (dedicated, never aliased)
    unsigned* bev = (unsigned*)ws;
    _Float16* x1h = (_Float16*)(ws + 8388608);
    _Float16* x3h = (_Float16*)ws;
    _Float16* wh  = (_Float16*)(ws + 16777216);
    float* tv  = ws + 16786432;
    float* outp = (float*)d_out;

    k_prep<<<2057, 256, 0, stream>>>((uint4*)bev, w3, b3, g3, be3, m3, v3, wh, tv);
    k_rasterize<<<(n + 255)/256, 256, 0, stream>>>(points, bev, n);
    k_conv1<<<4096, 256, 0, stream>>>(bev, w0, b0, g0, be0, m0, v0, x1h);
    k_conv2dw<<<1024, 256, 0, stream>>>(x1h, w1, b1, g1, be1, m1, v1,
                                        wdw, bdw, wpw, bpw, g2, be2, m2, v2, x3h);
    k_conv3m<<<512, 256, 0, stream>>>(x3h, wh, tv, outp);
}

// Round 16
// 132.477 us; speedup vs baseline: 1.0523x; 1.0523x over previous
//
#include <hip/hip_runtime.h>
#include <cstddef>

#define H_IN 1024
#define W_IN 1024
#define BN_EPS 1e-5f

typedef float f32x4 __attribute__((ext_vector_type(4)));
typedef _Float16 f16x8 __attribute__((ext_vector_type(8)));

// order-preserving float<->u32 bijection: enc monotonic, enc(x)>0 for all reals,
// so 0x00000000 is the identity for unsigned atomicMax.
__device__ __forceinline__ unsigned encF(float f) {
    unsigned u = __float_as_uint(f);
    return (u & 0x80000000u) ? ~u : (u | 0x80000000u);
}
__device__ __forceinline__ float decF(unsigned e, float untouched) {
    if (e == 0u) return untouched;
    unsigned bits = (e & 0x80000000u) ? (e ^ 0x80000000u) : ~e;
    return __uint_as_float(bits);
}

// ---------------- stage -1: zero bev + prep conv3 weights (one launch) ----------------
// blocks 0..2047: uint4-zero the 33.5MB bev. blocks 2048..2056: wprep tap blockIdx-2048.
__global__ void k_prep(uint4* __restrict__ bevq,
                       const float* __restrict__ w3, const float* __restrict__ b3,
                       const float* __restrict__ g3, const float* __restrict__ be3,
                       const float* __restrict__ m3, const float* __restrict__ v3,
                       _Float16* __restrict__ wh, float* __restrict__ tv) {
    int bid = blockIdx.x;
    int t = threadIdx.x;
    if (bid < 2048) {
        int i = bid * 256 + t;
        uint4 z = {0u, 0u, 0u, 0u};
        #pragma unroll
        for (int j = 0; j < 4; j++)
            bevq[(size_t)j*524288 + i] = z;
        return;
    }
    __shared__ float sSh[64];
    if (t < 64) {
        float s = g3[t] / sqrtf(v3[t] + BN_EPS);
        sSh[t] = s;
        if (bid == 2048) tv[t] = (b3[t] - m3[t]) * s + be3[t];
    }
    __syncthreads();
    int khw = bid - 2048;
    for (int i = t; i < 2048; i += 256) {
        int oc = i >> 5;                       // i = oc*32 + ic
        wh[khw*2048 + i] = (_Float16)(w3[(size_t)i*9 + khw] * sSh[oc]);
    }
}

// ---------------- stage 0: rasterize into encoded interleaved BEV ----------------
// r10/r13/r14 measured: 1pt/thread == 4pt-loop == 8pt-phase-batch (all ~41 us) ->
// bound by device-scope scattered atomic RMW throughput (~23G/s). Hardware wall.
__global__ void k_rasterize(const float* __restrict__ pts, unsigned* __restrict__ bev, int n) {
    int i = blockIdx.x * blockDim.x + threadIdx.x;
    if (i >= n) return;
    float fb  = pts[(size_t)i*5+0];
    float px  = pts[(size_t)i*5+1];
    float py  = pts[(size_t)i*5+2];
    float pz  = pts[(size_t)i*5+3];
    float pit = pts[(size_t)i*5+4];
    const float XS = (float)(1024.0/69.12);
    const float YS = (float)(1024.0/79.36);
    int xp = (int)(px * XS);                  // trunc toward zero, same as astype(int32)
    int yp = (int)((py + 39.68f) * YS);
    if (xp < 0 || xp >= W_IN || yp < 0 || yp >= H_IN) return;
    int b = (int)fb;
    size_t off = (((size_t)b * H_IN + yp) * W_IN + xp) * 2;
    atomicMax(bev + off,     encF(pz));
    atomicMax(bev + off + 1, encF(pit));
}

// ---------------- stage 1: conv1(2->8,3x3,pad1)+BN+ReLU+maxpool2 -> f16 NHWC ----------------
// in:  bev u32 [4,1024,1024,2] encoded   out: x1h [4,512,512,8] f16 (NHWC: one 16B store)
__global__ __launch_bounds__(256, 4) void k_conv1(
                        const unsigned* __restrict__ bev, const float* __restrict__ w0,
                        const float* __restrict__ b0, const float* __restrict__ g0,
                        const float* __restrict__ be0, const float* __restrict__ m0,
                        const float* __restrict__ v0, _Float16* __restrict__ out) {
    __shared__ float wS[144];       // [8][2][3][3]
    __shared__ float sS[8], tS[8];
    int t = threadIdx.x;
    if (t < 144) wS[t] = w0[t];
    if (t < 8) {
        float s = g0[t] / sqrtf(v0[t] + BN_EPS);
        sS[t] = s;
        tS[t] = (b0[t] - m0[t]) * s + be0[t];
    }
    __syncthreads();
    int idx = blockIdx.x * 256 + t;                 // 4*512*512 total
    int x = idx & 511, y = (idx >> 9) & 511, b = idx >> 18;
    const unsigned* base = bev + (size_t)b * H_IN * W_IN * 2;
    float in[2][4][4];
    #pragma unroll
    for (int r = 0; r < 4; r++) {
        int iy = 2*y - 1 + r;
        #pragma unroll
        for (int cc = 0; cc < 4; cc++) {
            int ix = 2*x - 1 + cc;
            if (iy >= 0 && iy < H_IN && ix >= 0 && ix < W_IN) {
                const unsigned* p2 = base + ((size_t)iy*W_IN + ix)*2;
                in[0][r][cc] = decF(p2[0], -10.0f);
                in[1][r][cc] = decF(p2[1], 0.0f);
            } else {
                in[0][r][cc] = 0.0f;
                in[1][r][cc] = 0.0f;
            }
        }
    }
    f16x8 ov;
    #pragma unroll
    for (int oc = 0; oc < 8; oc++) {
        float mx = 0.0f;                            // post-ReLU values are >= 0
        #pragma unroll
        for (int py = 0; py < 2; py++)
            #pragma unroll
            for (int px = 0; px < 2; px++) {
                float acc = 0.0f;
                #pragma unroll
                for (int c = 0; c < 2; c++)
                    #pragma unroll
                    for (int kh = 0; kh < 3; kh++)
                        #pragma unroll
                        for (int kw = 0; kw < 3; kw++)
                            acc += in[c][py+kh][px+kw] * wS[((oc*2+c)*3+kh)*3+kw];
                acc = fmaxf(acc * sS[oc] + tS[oc], 0.0f);
                mx = fmaxf(mx, acc);
            }
        ov[oc] = (_Float16)mx;
    }
    *(f16x8*)(out + ((size_t)((b*512 + y)*512 + x)) * 8) = ov;
}

// ---------------- stage 2: conv2 grouped(8) via MFMA + BN + ReLU + maxpool2 -> f16 NHWC ----------------
// (r13-validated MFMA core) in: x1h [4,512,512,8] f16 NHWC   out: x2h [4,256,256,16] f16 NHWC
// r16: f16 NHWC output halves write traffic (16.8 -> 8.4 MB).
__global__ __launch_bounds__(256, 4) void k_conv2m(
                        const _Float16* __restrict__ x1, const float* __restrict__ w1,
                        const float* __restrict__ b1, const float* __restrict__ g1,
                        const float* __restrict__ be1, const float* __restrict__ m1,
                        const float* __restrict__ v1, _Float16* __restrict__ out) {
    __shared__ _Float16 As[10][66][8];      // 10 pre-pool rows x 66 px x 8ch = 10560 B
    __shared__ float wS[144], sS[16], tS[16];
    int t = threadIdx.x;
    if (t < 144) wS[t] = w1[t];
    if (t < 16) {
        float s = g1[t] / sqrtf(v1[t] + BN_EPS);
        sS[t] = s;
        tS[t] = (b1[t] - m1[t]) * s + be1[t];
    }
    int lane = t & 63, w = t >> 6;
    int l15 = lane & 15, l4 = lane >> 4;
    int bi = blockIdx.x;
    int xt = bi & 7, yg = (bi >> 3) & 63, b = bi >> 9;
    int x0 = xt * 64;           // pre-pool col base (512-grid)
    int y0 = yg * 8;            // pre-pool row base
    __syncthreads();

    f16x8 Bf[3];
    #pragma unroll
    for (int kh = 0; kh < 3; kh++) {
        f16x8 z = {0,0,0,0,0,0,0,0};
        if (l4 < 3) z[l15 >> 1] = (_Float16)(wS[l15*9 + kh*3 + l4] * sS[l15]);
        Bf[kh] = z;
    }
    float tvv = tS[l15];

    const _Float16* base = x1 + (size_t)b * 512 * 512 * 8;
    for (int s = t; s < 660; s += 256) {
        int row = s / 66, px = s - row * 66;
        int gy = y0 - 1 + row, gx = x0 - 1 + px;
        f16x8 v = {0,0,0,0,0,0,0,0};
        if (gy >= 0 && gy < 512 && gx >= 0 && gx < 512)
            v = *(const f16x8*)(base + ((size_t)gy*512 + gx)*8);
        *(f16x8*)&As[row][px][0] = v;
    }
    __syncthreads();

    for (int ti = 0; ti < 4; ti++) {
        f32x4 acc[2];
        acc[0] = (f32x4){0,0,0,0};
        acc[1] = (f32x4){0,0,0,0};
        #pragma unroll
        for (int kh = 0; kh < 3; kh++)
            #pragma unroll
            for (int f = 0; f < 2; f++) {
                f16x8 Af = {0,0,0,0,0,0,0,0};
                if (l4 < 3)
                    Af = *(const f16x8*)&As[2*ti + f + kh][w*16 + l15 + l4][0];
                acc[f] = __builtin_amdgcn_mfma_f32_16x16x32_f16(Af, Bf[kh], acc[f], 0, 0, 0);
            }
        int yp = yg*4 + ti;
        _Float16* ob = out + ((size_t)b*256 + yp) * 256 * 16;
        #pragma unroll
        for (int q = 0; q < 2; q++) {
            float v0 = fmaxf(fmaxf(acc[0][2*q]   + tvv, 0.f),
                             fmaxf(acc[0][2*q+1] + tvv, 0.f));
            float v1_ = fmaxf(fmaxf(acc[1][2*q]   + tvv, 0.f),
                              fmaxf(acc[1][2*q+1] + tvv, 0.f));
            int xp = xt*32 + w*8 + 2*l4 + q;
            ob[(size_t)xp*16 + l15] = (_Float16)fmaxf(v0, v1_);   // NHWC: lanes l15 -> 32B runs
        }
    }
}

// ---------------- stage 3: depthwise + pointwise + BN + ReLU -> f16 NHWC ----------------
// in: x2h [4,256,256,16] f16 NHWC   out: x3h [4,256,256,32] f16
// r16: staging from NHWC f16 = 2 x 16B vector loads per pixel (was 16 scalar f32 loads);
// LDS patch stays f32 planar so the r5-validated compute phase is unchanged.
__global__ __launch_bounds__(256, 4) void k_dwpw(
                       const _Float16* __restrict__ x2, const float* __restrict__ wdw,
                       const float* __restrict__ bdw, const float* __restrict__ wpw,
                       const float* __restrict__ bpw, const float* __restrict__ g2,
                       const float* __restrict__ be2, const float* __restrict__ m2,
                       const float* __restrict__ v2, _Float16* __restrict__ out) {
    __shared__ float patch[16*10*36];   // 23040 B, planar [ic][10][36]
    __shared__ float wdwS[144];         // [16][3][3]
    __shared__ float bdwS[16];
    __shared__ float wpwS[512];         // [32][16]
    __shared__ float sS[32], tS[32];
    int t = threadIdx.x;
    if (t < 144) wdwS[t] = wdw[t];
    if (t < 16) bdwS[t] = bdw[t];
    for (int i = t; i < 512; i += 256) wpwS[i] = wpw[i];
    if (t < 32) {
        float s = g2[t] / sqrtf(v2[t] + BN_EPS);
        sS[t] = s;
        tS[t] = (bpw[t] - m2[t]) * s + be2[t];
    }

    int bi = blockIdx.x;                 // 1024 = 8 tx * 32 ty * 4 b
    int tx = bi & 7, ty = (bi >> 3) & 31, b = bi >> 8;
    int x0 = tx * 32, y0 = ty * 8;
    const _Float16* base = x2 + (size_t)b * 256 * 256 * 16;

    for (int i = t; i < 340; i += 256) {
        int r = i / 34, c = i - r * 34;
        int gy = y0 - 1 + r, gx = x0 - 1 + c;
        if (gy >= 0 && gy < 256 && gx >= 0 && gx < 256) {
            const _Float16* p = base + ((size_t)gy*256 + gx)*16;
            f16x8 v0 = *(const f16x8*)p;
            f16x8 v1 = *(const f16x8*)(p + 8);
            #pragma unroll
            for (int j = 0; j < 8; j++) {
                patch[j*360     + r*36 + c] = (float)v0[j];
                patch[(j+8)*360 + r*36 + c] = (float)v1[j];
            }
        } else {
            #pragma unroll
            for (int j = 0; j < 16; j++)
                patch[j*360 + r*36 + c] = 0.0f;
        }
    }
    __syncthreads();

    int px = t & 31, pyy = t >> 5;       // pixel within tile
    int x = x0 + px, y = y0 + pyy;

    float dv[16];
    #pragma unroll
    for (int ic = 0; ic < 16; ic++) {
        float d = bdwS[ic];
        #pragma unroll
        for (int r = 0; r < 3; r++)
            #pragma unroll
            for (int c = 0; c < 3; c++)
                d += patch[(ic*10 + pyy + r)*36 + px + c] * wdwS[ic*9 + r*3 + c];
        dv[ic] = d;
    }

    _Float16* ob = out + ((size_t)((b*256 + y)*256 + x)) * 32;
    #pragma unroll
    for (int q = 0; q < 4; q++) {
        f16x8 ov;
        #pragma unroll
        for (int j = 0; j < 8; j++) {
            int oc = q*8 + j;
            float a = 0.0f;
            #pragma unroll
            for (int ic = 0; ic < 16; ic++)
                a += dv[ic] * wpwS[oc*16+ic];
            ov[j] = (_Float16)fmaxf(a*sS[oc] + tS[oc], 0.0f);
        }
        *(f16x8*)(ob + q*8) = ov;
    }
}

// ---------------- stage 4: conv3 via MFMA f16 implicit GEMM + BN + ReLU + maxpool2 ----------------
// in: x3h [4,256,256,32] f16 NHWC, wh [9][64][32] f16, tv[64] f32
// out: d_out [4,64,128,128] f32
// r8-validated: stage 10 rows ONCE per block (52.8 KB LDS), 1 barrier, 4 row-tiles.
// (r16 note: per-wave oc-split rejected -- it shifts MFMA:ds_read from 4:1 to 1:1,
//  LDS-read-bound at ~12cy/b128 vs ~4.8cy/MFMA.)
__global__ __launch_bounds__(256, 2) void k_conv3m(const _Float16* __restrict__ xh,
                                                   const _Float16* __restrict__ wh,
                                                   const float* __restrict__ tv,
                                                   float* __restrict__ out) {
    __shared__ _Float16 As[10*66*40];       // rows x px x ic(pad 32->40), 52800 B
    int t = threadIdx.x;
    int lane = t & 63, w = t >> 6;
    int l15 = lane & 15, l4 = lane >> 4;
    int bi = blockIdx.x;
    int xt = bi & 3, yg = (bi >> 2) & 31, b = bi >> 7;
    int x0 = xt * 64;
    int y0 = yg * 8;                        // pre-pool row base (256-grid)

    f16x8 Bf[9][4];
    #pragma unroll
    for (int khw = 0; khw < 9; khw++)
        #pragma unroll
        for (int g = 0; g < 4; g++)
            Bf[khw][g] = *(const f16x8*)(wh + ((khw*64 + g*16 + l15)*32 + 8*l4));

    float tvv[4];
    #pragma unroll
    for (int g = 0; g < 4; g++) tvv[g] = tv[g*16 + l15];

    for (int s = t; s < 660; s += 256) {
        int row = s / 66, px = s - row*66;
        int gy = y0 - 1 + row, gx = x0 - 1 + px;
        float4* dst = (float4*)&As[(row*66 + px)*40];
        if (gy >= 0 && gy < 256 && gx >= 0 && gx < 256) {
            const float4* src = (const float4*)(xh + ((size_t)((b*256 + gy)*256 + gx)) * 32);
            #pragma unroll
            for (int j = 0; j < 4; j++) dst[j] = src[j];
        } else {
            float4 z = make_float4(0.f, 0.f, 0.f, 0.f);
            #pragma unroll
            for (int j = 0; j < 4; j++) dst[j] = z;
        }
    }
    __syncthreads();

    for (int ti = 0; ti < 4; ti++) {
        int ypool = yg*4 + ti;              // pooled row 0..127
        f32x4 acc[2][4];
        #pragma unroll
        for (int f = 0; f < 2; f++)
            #pragma unroll
            for (int g = 0; g < 4; g++)
                acc[f][g] = (f32x4){0.f, 0.f, 0.f, 0.f};

        #pragma unroll
        for (int kh = 0; kh < 3; kh++)
            #pragma unroll
            for (int kw = 0; kw < 3; kw++) {
                f16x8 Af[2];
                #pragma unroll
                for (int f = 0; f < 2; f++) {
                    int row = 2*ti + f + kh;                // staged row idx
                    int px = w*16 + l15 + kw;               // staged px idx
                    Af[f] = *(const f16x8*)&As[(row*66 + px)*40 + 8*l4];
                }
                #pragma unroll
                for (int f = 0; f < 2; f++)
                    #pragma unroll
                    for (int g = 0; g < 4; g++)
                        acc[f][g] = __builtin_amdgcn_mfma_f32_16x16x32_f16(
                            Af[f], Bf[kh*3+kw][g], acc[f][g], 0, 0, 0);
            }

        #pragma unroll
        for (int g = 0; g < 4; g++) {
            int oc = g*16 + l15;
            #pragma unroll
            for (int q = 0; q < 2; q++) {
                float v0 = fmaxf(fmaxf(acc[0][g][2*q]   + tvv[g], 0.f),
                                 fmaxf(acc[0][g][2*q+1] + tvv[g], 0.f));
                float v1 = fmaxf(fmaxf(acc[1][g][2*q]   + tvv[g], 0.f),
                                 fmaxf(acc[1][g][2*q+1] + tvv[g], 0.f));
                int px = x0/2 + w*8 + 2*l4 + q;
                out[(((size_t)b*64 + oc)*128 + ypool)*128 + px] = fmaxf(v0, v1);
            }
        }
    }
}

extern "C" void kernel_launch(void* const* d_in, const int* in_sizes, int n_in,
                              void* d_out, int out_size, void* d_ws, size_t ws_size,
                              hipStream_t stream) {
    const float* points = (const float*)d_in[0];
    int n = in_sizes[0] / 5;
    const float* w0  = (const float*)d_in[2];
    const float* b0  = (const float*)d_in[3];
    const float* g0  = (const float*)d_in[4];
    const float* be0 = (const float*)d_in[5];
    const float* m0  = (const float*)d_in[6];
    const float* v0  = (const float*)d_in[7];
    const float* w1  = (const float*)d_in[8];
    const float* b1  = (const float*)d_in[9];
    const float* g1  = (const float*)d_in[10];
    const float* be1 = (const float*)d_in[11];
    const float* m1  = (const float*)d_in[12];
    const float* v1  = (const float*)d_in[13];
    const float* wdw = (const float*)d_in[14];
    const float* bdw = (const float*)d_in[15];
    const float* wpw = (const float*)d_in[16];
    const float* bpw = (const float*)d_in[17];
    const float* g2  = (const float*)d_in[18];
    const float* be2 = (const float*)d_in[19];
    const float* m2  = (const float*)d_in[20];
    const float* v2  = (const float*)d_in[21];
    const float* w3  = (const float*)d_in[22];
    const float* b3  = (const float*)d_in[23];
    const float* g3  = (const float*)d_in[24];
    const float* be3 = (const float*)d_in[25];
    const float* m3  = (const float*)d_in[26];
    const float* v3  = (const float*)d_in[27];

    float* ws  = (float*)d_ws;
    // layout (float indices into ws):
    //   bev  u32 [4,1024,1024,2] : 0 .. 8,388,608          (dead after conv1)
    //   x1h  f16 [4,512,512,8]   : 8,388,608 .. 12,582,912 (dead after conv2m)
    //   x2h  f16 [4,256,256,16]  : 0 .. 2,097,152          (reuses bev; dead after dwpw)
    //   x3h  f16 [4,256,256,32]  : 8,388,608 .. 12,582,912 (reuses x1h; dead after conv3m)
    //   wh   f16 [9][64][32]     : 16,777,216 ..           (dedicated, never aliased)
    unsigned* bev = (unsigned*)ws;
    _Float16* x1h = (_Float16*)(ws + 8388608);
    _Float16* x2h = (_Float16*)ws;
    _Float16* x3h = (_Float16*)(ws + 8388608);
    _Float16* wh  = (_Float16*)(ws + 16777216);
    float* tv  = ws + 16786432;
    float* outp = (float*)d_out;

    k_prep<<<2057, 256, 0, stream>>>((uint4*)bev, w3, b3, g3, be3, m3, v3, wh, tv);
    k_rasterize<<<(n + 255)/256, 256, 0, stream>>>(points, bev, n);
    k_conv1<<<4096, 256, 0, stream>>>(bev, w0, b0, g0, be0, m0, v0, x1h);
    k_conv2m<<<2048, 256, 0, stream>>>(x1h, w1, b1, g1, be1, m1, v1, x2h);
    k_dwpw<<<1024, 256, 0, stream>>>(x2h, wdw, bdw, wpw, bpw, g2, be2, m2, v2, x3h);
    k_conv3m<<<512, 256, 0, stream>>>(x3h, wh, tv, outp);
}

// Round 18
// 125.587 us; speedup vs baseline: 1.1100x; 1.0549x over previous
//
#include <hip/hip_runtime.h>
#include <cstddef>

#define H_IN 1024
#define W_IN 1024
#define BN_EPS 1e-5f

typedef float f32x4 __attribute__((ext_vector_type(4)));
typedef _Float16 f16x8 __attribute__((ext_vector_type(8)));
typedef __fp16 h16x2 __attribute__((ext_vector_type(2)));   // builtin-compatible half2

// order-preserving float<->u32 bijection: enc monotonic.
// z-plane is PRE-FILLED with encF(-10.0f)=0x3EDFFFFF (r17) so decode is the pure
// inverse bijection (branchless); i-plane identity stays 0 (i>=0 -> dec = e&0x7fffffff).
__device__ __forceinline__ unsigned encF(float f) {
    unsigned u = __float_as_uint(f);
    return (u & 0x80000000u) ? ~u : (u | 0x80000000u);
}
__device__ __forceinline__ float dec_z(unsigned e) {
    unsigned bits = (e & 0x80000000u) ? (e ^ 0x80000000u) : ~e;
    return __uint_as_float(bits);
}
__device__ __forceinline__ h16x2 u2h(unsigned u) {
    union { unsigned u; h16x2 h; } c; c.u = u; return c.h;
}
__device__ __forceinline__ unsigned h2u(h16x2 h) {
    union { h16x2 h; unsigned u; } c; c.h = h; return c.u;
}

#define ENCZ_M10 0x3EDFFFFFu   // encF(-10.0f)

// ---------------- stage -1: fill bev (z=enc(-10), i=0) + prep conv3 weights ----------------
// blocks 0..2047: uint4-fill the 33.5MB bev. blocks 2048..2056: wprep tap blockIdx-2048.
__global__ void k_prep(uint4* __restrict__ bevq,
                       const float* __restrict__ w3, const float* __restrict__ b3,
                       const float* __restrict__ g3, const float* __restrict__ be3,
                       const float* __restrict__ m3, const float* __restrict__ v3,
                       _Float16* __restrict__ wh, float* __restrict__ tv) {
    int bid = blockIdx.x;
    int t = threadIdx.x;
    if (bid < 2048) {
        int i = bid * 256 + t;
        uint4 z = {ENCZ_M10, 0u, ENCZ_M10, 0u};   // (z,i,z,i) interleaved cells
        #pragma unroll
        for (int j = 0; j < 4; j++)
            bevq[(size_t)j*524288 + i] = z;
        return;
    }
    __shared__ float sSh[64];
    if (t < 64) {
        float s = g3[t] / sqrtf(v3[t] + BN_EPS);
        sSh[t] = s;
        if (bid == 2048) tv[t] = (b3[t] - m3[t]) * s + be3[t];
    }
    __syncthreads();
    int khw = bid - 2048;
    for (int i = t; i < 2048; i += 256) {
        int oc = i >> 5;                       // i = oc*32 + ic
        wh[khw*2048 + i] = (_Float16)(w3[(size_t)i*9 + khw] * sSh[oc]);
    }
}

// ---------------- stage 0: rasterize into encoded interleaved BEV ----------------
// r10/r13/r14 measured: 1pt/thread == 4pt-loop == 8pt-phase-batch (all ~41 us) ->
// bound by device-scope scattered atomic RMW throughput (~23G/s). Hardware wall.
// z-floor is enc(-10) (< enc(z) for all z > -10, monotone) -> atomicMax still correct.
__global__ void k_rasterize(const float* __restrict__ pts, unsigned* __restrict__ bev, int n) {
    int i = blockIdx.x * blockDim.x + threadIdx.x;
    if (i >= n) return;
    float fb  = pts[(size_t)i*5+0];
    float px  = pts[(size_t)i*5+1];
    float py  = pts[(size_t)i*5+2];
    float pz  = pts[(size_t)i*5+3];
    float pit = pts[(size_t)i*5+4];
    const float XS = (float)(1024.0/69.12);
    const float YS = (float)(1024.0/79.36);
    int xp = (int)(px * XS);                  // trunc toward zero, same as astype(int32)
    int yp = (int)((py + 39.68f) * YS);
    if (xp < 0 || xp >= W_IN || yp < 0 || yp >= H_IN) return;
    int b = (int)fb;
    size_t off = (((size_t)b * H_IN + yp) * W_IN + xp) * 2;
    atomicMax(bev + off,     encF(pz));
    atomicMax(bev + off + 1, encF(pit));
}

// ---------------- stage 1: conv1 via v_dot2_f32_f16 + BN + ReLU + maxpool2 -> f16 NHWC ----------------
// in:  bev u32 [4,1024,1024,2] encoded   out: x1h [4,512,512,8] f16
// r17: each bev cell is a natural (z,i) channel pair -> one fdot2 per tap (2 FMA,
// f32 accum): 288 dot2 replaces 576 scalar fmac. BN scale folded into f16 weight
// pairs in LDS (12-slot padded rows -> 16B-aligned vector reads, 9 regs live/oc).
__global__ __launch_bounds__(256, 4) void k_conv1(
                        const unsigned* __restrict__ bev, const float* __restrict__ w0,
                        const float* __restrict__ b0, const float* __restrict__ g0,
                        const float* __restrict__ be0, const float* __restrict__ m0,
                        const float* __restrict__ v0, _Float16* __restrict__ out) {
    __shared__ unsigned w2S[96];    // [8 oc][12] packed f16x2 (wz*s, wi*s); taps 9..11 = 0
    __shared__ float tS[8];
    int t = threadIdx.x;
    if (t < 96) {
        int oc = t / 12, tap = t - oc*12;
        unsigned pk = 0u;
        if (tap < 9) {
            float s = g0[oc] / sqrtf(v0[oc] + BN_EPS);
            float wz = w0[oc*18 + tap]     * s;   // [oc][c=0][tap]
            float wi = w0[oc*18 + 9 + tap] * s;   // [oc][c=1][tap]
            h16x2 p = __builtin_amdgcn_cvt_pkrtz(wz, wi);
            pk = h2u(p);
        }
        w2S[t] = pk;
    }
    if (t < 8) {
        float s = g0[t] / sqrtf(v0[t] + BN_EPS);
        tS[t] = (b0[t] - m0[t]) * s + be0[t];
    }
    __syncthreads();
    int idx = blockIdx.x * 256 + t;                 // 4*512*512 total
    int x = idx & 511, y = (idx >> 9) & 511, b = idx >> 18;
    const unsigned* base = bev + (size_t)b * H_IN * W_IN * 2;

    h16x2 in2[4][4];
    h16x2 zero2 = {(__fp16)0.0f, (__fp16)0.0f};
    #pragma unroll
    for (int r = 0; r < 4; r++) {
        int iy = 2*y - 1 + r;
        #pragma unroll
        for (int cc = 0; cc < 4; cc++) {
            int ix = 2*x - 1 + cc;
            if (iy >= 0 && iy < H_IN && ix >= 0 && ix < W_IN) {
                uint2 u = *(const uint2*)(base + ((size_t)iy*W_IN + ix)*2);
                in2[r][cc] = __builtin_amdgcn_cvt_pkrtz(
                    dec_z(u.x), __uint_as_float(u.y & 0x7fffffffu));
            } else {
                in2[r][cc] = zero2;     // conv zero-pad (NOT -10)
            }
        }
    }

    f16x8 ov;
    #pragma unroll
    for (int oc = 0; oc < 8; oc++) {
        uint4 wa = *(const uint4*)&w2S[oc*12];      // taps 0..3 (48B-aligned)
        uint4 wb = *(const uint4*)&w2S[oc*12 + 4];  // taps 4..7
        unsigned w8 = w2S[oc*12 + 8];               // tap 8
        float tvb = tS[oc];
        float mx = 0.0f;                            // post-ReLU >= 0
        #pragma unroll
        for (int qy = 0; qy < 2; qy++)
            #pragma unroll
            for (int qx = 0; qx < 2; qx++) {
                float a = 0.0f;
                a = __builtin_amdgcn_fdot2(in2[qy+0][qx+0], u2h(wa.x), a, false);
                a = __builtin_amdgcn_fdot2(in2[qy+0][qx+1], u2h(wa.y), a, false);
                a = __builtin_amdgcn_fdot2(in2[qy+0][qx+2], u2h(wa.z), a, false);
                a = __builtin_amdgcn_fdot2(in2[qy+1][qx+0], u2h(wa.w), a, false);
                a = __builtin_amdgcn_fdot2(in2[qy+1][qx+1], u2h(wb.x), a, false);
                a = __builtin_amdgcn_fdot2(in2[qy+1][qx+2], u2h(wb.y), a, false);
                a = __builtin_amdgcn_fdot2(in2[qy+2][qx+0], u2h(wb.z), a, false);
                a = __builtin_amdgcn_fdot2(in2[qy+2][qx+1], u2h(wb.w), a, false);
                a = __builtin_amdgcn_fdot2(in2[qy+2][qx+2], u2h(w8),   a, false);
                mx = fmaxf(mx, fmaxf(a + tvb, 0.0f));
            }
        ov[oc] = (_Float16)mx;
    }
    *(f16x8*)(out + ((size_t)((b*512 + y)*512 + x)) * 8) = ov;
}

// ---------------- stage 2: conv2 grouped(8) via MFMA + BN + ReLU + maxpool2 -> f16 NHWC ----------------
// (r13-validated MFMA core) in: x1h [4,512,512,8] f16 NHWC   out: x2h [4,256,256,16] f16 NHWC
__global__ __launch_bounds__(256, 4) void k_conv2m(
                        const _Float16* __restrict__ x1, const float* __restrict__ w1,
                        const float* __restrict__ b1, const float* __restrict__ g1,
                        const float* __restrict__ be1, const float* __restrict__ m1,
                        const float* __restrict__ v1, _Float16* __restrict__ out) {
    __shared__ _Float16 As[10][66][8];      // 10 pre-pool rows x 66 px x 8ch = 10560 B
    __shared__ float wS[144], sS[16], tS[16];
    int t = threadIdx.x;
    if (t < 144) wS[t] = w1[t];
    if (t < 16) {
        float s = g1[t] / sqrtf(v1[t] + BN_EPS);
        sS[t] = s;
        tS[t] = (b1[t] - m1[t]) * s + be1[t];
    }
    int lane = t & 63, w = t >> 6;
    int l15 = lane & 15, l4 = lane >> 4;
    int bi = blockIdx.x;
    int xt = bi & 7, yg = (bi >> 3) & 63, b = bi >> 9;
    int x0 = xt * 64;           // pre-pool col base (512-grid)
    int y0 = yg * 8;            // pre-pool row base
    __syncthreads();

    f16x8 Bf[3];
    #pragma unroll
    for (int kh = 0; kh < 3; kh++) {
        f16x8 z = {0,0,0,0,0,0,0,0};
        if (l4 < 3) z[l15 >> 1] = (_Float16)(wS[l15*9 + kh*3 + l4] * sS[l15]);
        Bf[kh] = z;
    }
    float tvv = tS[l15];

    const _Float16* base = x1 + (size_t)b * 512 * 512 * 8;
    for (int s = t; s < 660; s += 256) {
        int row = s / 66, px = s - row * 66;
        int gy = y0 - 1 + row, gx = x0 - 1 + px;
        f16x8 v = {0,0,0,0,0,0,0,0};
        if (gy >= 0 && gy < 512 && gx >= 0 && gx < 512)
            v = *(const f16x8*)(base + ((size_t)gy*512 + gx)*8);
        *(f16x8*)&As[row][px][0] = v;
    }
    __syncthreads();

    for (int ti = 0; ti < 4; ti++) {
        f32x4 acc[2];
        acc[0] = (f32x4){0,0,0,0};
        acc[1] = (f32x4){0,0,0,0};
        #pragma unroll
        for (int kh = 0; kh < 3; kh++)
            #pragma unroll
            for (int f = 0; f < 2; f++) {
                f16x8 Af = {0,0,0,0,0,0,0,0};
                if (l4 < 3)
                    Af = *(const f16x8*)&As[2*ti + f + kh][w*16 + l15 + l4][0];
                acc[f] = __builtin_amdgcn_mfma_f32_16x16x32_f16(Af, Bf[kh], acc[f], 0, 0, 0);
            }
        int yp = yg*4 + ti;
        _Float16* ob = out + ((size_t)b*256 + yp) * 256 * 16;
        #pragma unroll
        for (int q = 0; q < 2; q++) {
            float v0 = fmaxf(fmaxf(acc[0][2*q]   + tvv, 0.f),
                             fmaxf(acc[0][2*q+1] + tvv, 0.f));
            float v1_ = fmaxf(fmaxf(acc[1][2*q]   + tvv, 0.f),
                              fmaxf(acc[1][2*q+1] + tvv, 0.f));
            int xp = xt*32 + w*8 + 2*l4 + q;
            ob[(size_t)xp*16 + l15] = (_Float16)fmaxf(v0, v1_);   // NHWC
        }
    }
}

// ---------------- stage 3: depthwise + pointwise + BN + ReLU -> f16 NHWC ----------------
// in: x2h [4,256,256,16] f16 NHWC   out: x3h [4,256,256,32] f16 (r16-validated)
__global__ __launch_bounds__(256, 4) void k_dwpw(
                       const _Float16* __restrict__ x2, const float* __restrict__ wdw,
                       const float* __restrict__ bdw, const float* __restrict__ wpw,
                       const float* __restrict__ bpw, const float* __restrict__ g2,
                       const float* __restrict__ be2, const float* __restrict__ m2,
                       const float* __restrict__ v2, _Float16* __restrict__ out) {
    __shared__ float patch[16*10*36];   // 23040 B, planar [ic][10][36]
    __shared__ float wdwS[144];         // [16][3][3]
    __shared__ float bdwS[16];
    __shared__ float wpwS[512];         // [32][16]
    __shared__ float sS[32], tS[32];
    int t = threadIdx.x;
    if (t < 144) wdwS[t] = wdw[t];
    if (t < 16) bdwS[t] = bdw[t];
    for (int i = t; i < 512; i += 256) wpwS[i] = wpw[i];
    if (t < 32) {
        float s = g2[t] / sqrtf(v2[t] + BN_EPS);
        sS[t] = s;
        tS[t] = (bpw[t] - m2[t]) * s + be2[t];
    }

    int bi = blockIdx.x;                 // 1024 = 8 tx * 32 ty * 4 b
    int tx = bi & 7, ty = (bi >> 3) & 31, b = bi >> 8;
    int x0 = tx * 32, y0 = ty * 8;
    const _Float16* base = x2 + (size_t)b * 256 * 256 * 16;

    for (int i = t; i < 340; i += 256) {
        int r = i / 34, c = i - r * 34;
        int gy = y0 - 1 + r, gx = x0 - 1 + c;
        if (gy >= 0 && gy < 256 && gx >= 0 && gx < 256) {
            const _Float16* p = base + ((size_t)gy*256 + gx)*16;
            f16x8 v0 = *(const f16x8*)p;
            f16x8 v1 = *(const f16x8*)(p + 8);
            #pragma unroll
            for (int j = 0; j < 8; j++) {
                patch[j*360     + r*36 + c] = (float)v0[j];
                patch[(j+8)*360 + r*36 + c] = (float)v1[j];
            }
        } else {
            #pragma unroll
            for (int j = 0; j < 16; j++)
                patch[j*360 + r*36 + c] = 0.0f;
        }
    }
    __syncthreads();

    int px = t & 31, pyy = t >> 5;       // pixel within tile
    int x = x0 + px, y = y0 + pyy;

    float dv[16];
    #pragma unroll
    for (int ic = 0; ic < 16; ic++) {
        float d = bdwS[ic];
        #pragma unroll
        for (int r = 0; r < 3; r++)
            #pragma unroll
            for (int c = 0; c < 3; c++)
                d += patch[(ic*10 + pyy + r)*36 + px + c] * wdwS[ic*9 + r*3 + c];
        dv[ic] = d;
    }

    _Float16* ob = out + ((size_t)((b*256 + y)*256 + x)) * 32;
    #pragma unroll
    for (int q = 0; q < 4; q++) {
        f16x8 ov;
        #pragma unroll
        for (int j = 0; j < 8; j++) {
            int oc = q*8 + j;
            float a = 0.0f;
            #pragma unroll
            for (int ic = 0; ic < 16; ic++)
                a += dv[ic] * wpwS[oc*16+ic];
            ov[j] = (_Float16)fmaxf(a*sS[oc] + tS[oc], 0.0f);
        }
        *(f16x8*)(ob + q*8) = ov;
    }
}

// ---------------- stage 4: conv3 via MFMA f16 implicit GEMM + BN + ReLU + maxpool2 ----------------
// in: x3h [4,256,256,32] f16 NHWC, wh [9][64][32] f16, tv[64] f32
// out: d_out [4,64,128,128] f32
// r8-validated: stage 10 rows ONCE per block (52.8 KB LDS), 1 barrier, 4 row-tiles.
__global__ __launch_bounds__(256, 2) void k_conv3m(const _Float16* __restrict__ xh,
                                                   const _Float16* __restrict__ wh,
                                                   const float* __restrict__ tv,
                                                   float* __restrict__ out) {
    __shared__ _Float16 As[10*66*40];       // rows x px x ic(pad 32->40), 52800 B
    int t = threadIdx.x;
    int lane = t & 63, w = t >> 6;
    int l15 = lane & 15, l4 = lane >> 4;
    int bi = blockIdx.x;
    int xt = bi & 3, yg = (bi >> 2) & 31, b = bi >> 7;
    int x0 = xt * 64;
    int y0 = yg * 8;                        // pre-pool row base (256-grid)

    f16x8 Bf[9][4];
    #pragma unroll
    for (int khw = 0; khw < 9; khw++)
        #pragma unroll
        for (int g = 0; g < 4; g++)
            Bf[khw][g] = *(const f16x8*)(wh + ((khw*64 + g*16 + l15)*32 + 8*l4));

    float tvv[4];
    #pragma unroll
    for (int g = 0; g < 4; g++) tvv[g] = tv[g*16 + l15];

    for (int s = t; s < 660; s += 256) {
        int row = s / 66, px = s - row*66;
        int gy = y0 - 1 + row, gx = x0 - 1 + px;
        float4* dst = (float4*)&As[(row*66 + px)*40];
        if (gy >= 0 && gy < 256 && gx >= 0 && gx < 256) {
            const float4* src = (const float4*)(xh + ((size_t)((b*256 + gy)*256 + gx)) * 32);
            #pragma unroll
            for (int j = 0; j < 4; j++) dst[j] = src[j];
        } else {
            float4 z = make_float4(0.f, 0.f, 0.f, 0.f);
            #pragma unroll
            for (int j = 0; j < 4; j++) dst[j] = z;
        }
    }
    __syncthreads();

    for (int ti = 0; ti < 4; ti++) {
        int ypool = yg*4 + ti;              // pooled row 0..127
        f32x4 acc[2][4];
        #pragma unroll
        for (int f = 0; f < 2; f++)
            #pragma unroll
            for (int g = 0; g < 4; g++)
                acc[f][g] = (f32x4){0.f, 0.f, 0.f, 0.f};

        #pragma unroll
        for (int kh = 0; kh < 3; kh++)
            #pragma unroll
            for (int kw = 0; kw < 3; kw++) {
                f16x8 Af[2];
                #pragma unroll
                for (int f = 0; f < 2; f++) {
                    int row = 2*ti + f + kh;                // staged row idx
                    int px = w*16 + l15 + kw;               // staged px idx
                    Af[f] = *(const f16x8*)&As[(row*66 + px)*40 + 8*l4];
                }
                #pragma unroll
                for (int f = 0; f < 2; f++)
                    #pragma unroll
                    for (int g = 0; g < 4; g++)
                        acc[f][g] = __builtin_amdgcn_mfma_f32_16x16x32_f16(
                            Af[f], Bf[kh*3+kw][g], acc[f][g], 0, 0, 0);
            }

        #pragma unroll
        for (int g = 0; g < 4; g++) {
            int oc = g*16 + l15;
            #pragma unroll
            for (int q = 0; q < 2; q++) {
                float v0 = fmaxf(fmaxf(acc[0][g][2*q]   + tvv[g], 0.f),
                                 fmaxf(acc[0][g][2*q+1] + tvv[g], 0.f));
                float v1 = fmaxf(fmaxf(acc[1][g][2*q]   + tvv[g], 0.f),
                                 fmaxf(acc[1][g][2*q+1] + tvv[g], 0.f));
                int px = x0/2 + w*8 + 2*l4 + q;
                out[(((size_t)b*64 + oc)*128 + ypool)*128 + px] = fmaxf(v0, v1);
            }
        }
    }
}

extern "C" void kernel_launch(void* const* d_in, const int* in_sizes, int n_in,
                              void* d_out, int out_size, void* d_ws, size_t ws_size,
                              hipStream_t stream) {
    const float* points = (const float*)d_in[0];
    int n = in_sizes[0] / 5;
    const float* w0  = (const float*)d_in[2];
    const float* b0  = (const float*)d_in[3];
    const float* g0  = (const float*)d_in[4];
    const float* be0 = (const float*)d_in[5];
    const float* m0  = (const float*)d_in[6];
    const float* v0  = (const float*)d_in[7];
    const float* w1  = (const float*)d_in[8];
    const float* b1  = (const float*)d_in[9];
    const float* g1  = (const float*)d_in[10];
    const float* be1 = (const float*)d_in[11];
    const float* m1  = (const float*)d_in[12];
    const float* v1  = (const float*)d_in[13];
    const float* wdw = (const float*)d_in[14];
    const float* bdw = (const float*)d_in[15];
    const float* wpw = (const float*)d_in[16];
    const float* bpw = (const float*)d_in[17];
    const float* g2  = (const float*)d_in[18];
    const float* be2 = (const float*)d_in[19];
    const float* m2  = (const float*)d_in[20];
    const float* v2  = (const float*)d_in[21];
    const float* w3  = (const float*)d_in[22];
    const float* b3  = (const float*)d_in[23];
    const float* g3  = (const float*)d_in[24];
    const float* be3 = (const float*)d_in[25];
    const float* m3  = (const float*)d_in[26];
    const float* v3  = (const float*)d_in[27];

    float* ws  = (float*)d_ws;
    // layout (float indices into ws):
    //   bev  u32 [4,1024,1024,2] : 0 .. 8,388,608          (dead after conv1)
    //   x1h  f16 [4,512,512,8]   : 8,388,608 .. 12,582,912 (dead after conv2m)
    //   x2h  f16 [4,256,256,16]  : 0 .. 2,097,152          (reuses bev; dead after dwpw)
    //   x3h  f16 [4,256,256,32]  : 8,388,608 .. 12,582,912 (reuses x1h; dead after conv3m)
    //   wh   f16 [9][64][32]     : 16,777,216 ..           (dedicated, never aliased)
    unsigned* bev = (unsigned*)ws;
    _Float16* x1h = (_Float16*)(ws + 8388608);
    _Float16* x2h = (_Float16*)ws;
    _Float16* x3h = (_Float16*)(ws + 8388608);
    _Float16* wh  = (_Float16*)(ws + 16777216);
    float* tv  = ws + 16786432;
    float* outp = (float*)d_out;

    k_prep<<<2057, 256, 0, stream>>>((uint4*)bev, w3, b3, g3, be3, m3, v3, wh, tv);
    k_rasterize<<<(n + 255)/256, 256, 0, stream>>>(points, bev, n);
    k_conv1<<<4096, 256, 0, stream>>>(bev, w0, b0, g0, be0, m0, v0, x1h);
    k_conv2m<<<2048, 256, 0, stream>>>(x1h, w1, b1, g1, be1, m1, v1, x2h);
    k_dwpw<<<1024, 256, 0, stream>>>(x2h, wdw, bdw, wpw, bpw, g2, be2, m2, v2, x3h);
    k_conv3m<<<512, 256, 0, stream>>>(x3h, wh, tv, outp);
}